// Round 4
// baseline (338.864 us; speedup 1.0000x reference)
//
#include <hip/hip_runtime.h>

// OutputNeuron scan: per-(b,n) element, independent recurrence over T=128.
//   syn = 0.9*syn + x_t ; mem = 0.95*mem + syn ; s = (mem>1) ; count += s ;
//   mem *= (1-s)
// Memory-bound: stream 268 MB of x once. R3 post-mortem: float4/thread gave
// only 2 waves/SIMD -> latency-stall dominated (~90 us vs 44 us floor).
// This version: one thread per float2 column (4 waves/SIMD, 2x TLP) and a
// depth-8 rotating nontemporal prefetch (16 MB in flight device-wide, 6x the
// BW*latency product of 2.5 MB).

typedef float vfloat2 __attribute__((ext_vector_type(2)));

#define NEURON_ALPHA 0.9f
#define NEURON_BETA  0.95f

#define NEURON_STEP(c)                                   \
    do {                                                 \
        syn[c] = NEURON_ALPHA * syn[c] + xt[c];          \
        mem[c] = NEURON_BETA  * mem[c] + syn[c];         \
        bool sp = (mem[c] > 1.0f);                       \
        cnt[c] += sp ? 1.0f : 0.0f;                      \
        mem[c]  = sp ? 0.0f : mem[c];                    \
    } while (0)

__global__ __launch_bounds__(256) void outneuron_scan_kernel(
    const float* __restrict__ x,
    const float* __restrict__ mem0,
    const float* __restrict__ syn0,
    const float* __restrict__ count0,
    float* __restrict__ out,
    int BN, int T)
{
    const int i2  = blockIdx.x * blockDim.x + threadIdx.x; // float2 column index
    const int idx = i2 << 1;
    if (idx >= BN) return;

    vfloat2 syn = *reinterpret_cast<const vfloat2*>(syn0   + idx);
    vfloat2 mem = *reinterpret_cast<const vfloat2*>(mem0   + idx);
    vfloat2 cnt = *reinterpret_cast<const vfloat2*>(count0 + idx);

    const vfloat2* xp = reinterpret_cast<const vfloat2*>(x) + i2;
    const size_t s2 = (size_t)(BN >> 1); // vfloat2 stride between timesteps

    // Prologue: fill the 8-deep pipeline (T = 128 >= 16).
    vfloat2 buf[8];
#pragma unroll
    for (int k = 0; k < 8; ++k)
        buf[k] = __builtin_nontemporal_load(xp + (size_t)k * s2);
    xp += 8 * s2;

    // Steady state: compute with the load issued 8 iterations ago; issue the
    // replacement immediately. Unroll 8 so buf[] indices are compile-time
    // constants (registers) and the wave waits at vmcnt(7), never vmcnt(0).
    int i = 0;
#pragma unroll 8
    for (; i < T - 8; ++i) {
        vfloat2 xt = buf[i & 7];
        buf[i & 7] = __builtin_nontemporal_load(xp);
        xp += s2;
        NEURON_STEP(0);
        NEURON_STEP(1);
    }

    // Epilogue: drain the last 8 buffered timesteps (no more loads).
#pragma unroll 8
    for (; i < T; ++i) {
        vfloat2 xt = buf[i & 7];
        NEURON_STEP(0);
        NEURON_STEP(1);
    }

    *reinterpret_cast<vfloat2*>(out + idx) = cnt;
}

extern "C" void kernel_launch(void* const* d_in, const int* in_sizes, int n_in,
                              void* d_out, int out_size, void* d_ws, size_t ws_size,
                              hipStream_t stream) {
    const float* x      = (const float*)d_in[0];
    const float* mem0   = (const float*)d_in[1];
    const float* syn0   = (const float*)d_in[2];
    const float* count0 = (const float*)d_in[3];
    float* out = (float*)d_out;

    const int BN = in_sizes[1];          // B*N = 524288 (divisible by 2)
    const int T  = in_sizes[0] / BN;     // 128

    const int n_threads = BN >> 1;       // one thread per float2 column
    dim3 block(256);
    dim3 grid((n_threads + block.x - 1) / block.x);
    outneuron_scan_kernel<<<grid, block, 0, stream>>>(x, mem0, syn0, count0, out, BN, T);
}